// Round 13
// baseline (1179.178 us; speedup 1.0000x reference)
//
#include <hip/hip_runtime.h>
#include <hip/hip_bf16.h>

// Decoder forward: B=2,T=1024,D=1024,H=16(hs=64),L=2,FF=4096,V=32000
// Outputs (f32, concat): logits[N,V], loss[1], maps[L,B,H,T,T], probs[N,D]
// Round 13: coalesced maps-write phase in attn_fused (was stride-16 scatter
// on the 268MB output); XCD-bijective swizzle on ALL GEMMs; PV unroll.
#define VSZ 32000
#define DM  1024
#define TSEQ 1024
#define BB  2
#define HH  16
#define LL  2
#define FFD 4096
#define NTOK (BB*TSEQ)   // 2048
#define QT  16           // q-rows per attn_fused block

static constexpr size_t LOGITS_OFF = 0;
static constexpr size_t LOSS_OFF   = (size_t)NTOK * VSZ;
static constexpr size_t MAPS_OFF   = LOSS_OFF + 1;
static constexpr size_t PROBS_OFF  = MAPS_OFF + (size_t)LL*BB*HH*TSEQ*TSEQ;

typedef __attribute__((ext_vector_type(8))) short bf8;
typedef __attribute__((ext_vector_type(4))) float f32x4;
typedef __attribute__((ext_vector_type(4))) short short4v;

__device__ __forceinline__ short f2bf(float f) {   // RTNE f32 -> bf16 bits
  union { float f; unsigned u; } v; v.f = f;
  unsigned r = v.u + 0x7FFFu + ((v.u >> 16) & 1u);
  return (short)(r >> 16);
}
__device__ __forceinline__ float bf2f(short s) {
  union { unsigned u; float f; } v; v.u = ((unsigned)(unsigned short)s) << 16;
  return v.f;
}

// Async global->LDS, 16 B/lane (dest = wave-uniform base + lane*16).
__device__ __forceinline__ void gload16(const void* g, void* l) {
  __builtin_amdgcn_global_load_lds(
      (const __attribute__((address_space(1))) void*)g,
      (__attribute__((address_space(3))) void*)l, 16, 0, 0);
}

// ---------------- reductions ----------------
__device__ __forceinline__ float block_sum256(float v, float* sh) {
#pragma unroll
  for (int off = 32; off; off >>= 1) v += __shfl_down(v, off);
  int wid = threadIdx.x >> 6, lane = threadIdx.x & 63;
  if (lane == 0) sh[wid] = v;
  __syncthreads();
  v = sh[0] + sh[1] + sh[2] + sh[3];
  __syncthreads();
  return v;
}
__device__ __forceinline__ float block_max256(float v, float* sh) {
#pragma unroll
  for (int off = 32; off; off >>= 1) v = fmaxf(v, __shfl_down(v, off));
  int wid = threadIdx.x >> 6, lane = threadIdx.x & 63;
  if (lane == 0) sh[wid] = v;
  __syncthreads();
  v = fmaxf(fmaxf(sh[0], sh[1]), fmaxf(sh[2], sh[3]));
  __syncthreads();
  return v;
}

// ---------------- fused weight transpose+convert (all layer weights) --------
static constexpr size_t PLW = (size_t)4 * DM * DM + (size_t)DM * FFD + (size_t)FFD * DM;
__global__ __launch_bounds__(256) void transpose_all(const float* __restrict__ wq,
    const float* __restrict__ wk, const float* __restrict__ wv,
    const float* __restrict__ proj_w, const float* __restrict__ ff_w1,
    const float* __restrict__ ff_w2, short* __restrict__ wt_base) {
  __shared__ float T[64][65];
  const int bid = blockIdx.x;
  const int l = bid / 3072, r = bid % 3072;
  short* qbase = wt_base + (size_t)l * PLW;
  const float* W; short* Wt; int K, N, tn, tk;
  if (r < 1024) {
    int s = r >> 8, rr = r & 255;
    W = (s == 0 ? wq : (s == 1 ? wk : (s == 2 ? wv : proj_w))) + (size_t)l * DM * DM;
    Wt = qbase + (size_t)s * DM * DM;
    K = DM; N = DM; tn = rr & 15; tk = rr >> 4;
  } else if (r < 2048) {
    int rr = r - 1024;
    W = ff_w1 + (size_t)l * DM * FFD; Wt = qbase + (size_t)4 * DM * DM;
    K = DM; N = FFD; tn = rr & 63; tk = rr >> 6;
  } else {
    int rr = r - 2048;
    W = ff_w2 + (size_t)l * FFD * DM; Wt = qbase + (size_t)4 * DM * DM + (size_t)DM * FFD;
    K = FFD; N = DM; tn = rr & 15; tk = rr >> 4;
  }
  const int n0 = tn * 64, k0 = tk * 64;
  const int tid = threadIdx.x;
  const int lr = tid >> 4, lc4 = (tid & 15) * 4;
#pragma unroll
  for (int p = 0; p < 4; ++p) {
    int k = lr + p * 16;
    float4 w = *(const float4*)&W[(size_t)(k0 + k) * N + n0 + lc4];
    T[k][lc4] = w.x; T[k][lc4+1] = w.y; T[k][lc4+2] = w.z; T[k][lc4+3] = w.w;
  }
  __syncthreads();
#pragma unroll
  for (int p = 0; p < 4; ++p) {
    int n = lr + p * 16;
    short4v s;
    s.x = f2bf(T[lc4  ][n]);
    s.y = f2bf(T[lc4+1][n]);
    s.z = f2bf(T[lc4+2][n]);
    s.w = f2bf(T[lc4+3][n]);
    *(short4v*)&Wt[(size_t)(n0 + n) * K + k0 + lc4] = s;
  }
}

// ---------------- single-weight transpose (lm_w) ----------------------------
__global__ __launch_bounds__(256) void transpose_cvt(const float* __restrict__ W,
    short* __restrict__ Wt, int K, int N) {
  __shared__ float T[64][65];
  const int n0 = blockIdx.x * 64, k0 = blockIdx.y * 64;
  const int tid = threadIdx.x;
  const int lr = tid >> 4, lc4 = (tid & 15) * 4;
#pragma unroll
  for (int p = 0; p < 4; ++p) {
    int k = lr + p * 16;
    float4 w = *(const float4*)&W[(size_t)(k0 + k) * N + n0 + lc4];
    T[k][lc4] = w.x; T[k][lc4+1] = w.y; T[k][lc4+2] = w.z; T[k][lc4+3] = w.w;
  }
  __syncthreads();
#pragma unroll
  for (int p = 0; p < 4; ++p) {
    int n = lr + p * 16;
    short4v s;
    s.x = f2bf(T[lc4  ][n]);
    s.y = f2bf(T[lc4+1][n]);
    s.z = f2bf(T[lc4+2][n]);
    s.w = f2bf(T[lc4+3][n]);
    *(short4v*)&Wt[(size_t)(n0 + n) * K + k0 + lc4] = s;
  }
}

// ---------------- embedding ----------------
__global__ __launch_bounds__(256) void embed_kernel(const int* __restrict__ idx,
    const float* __restrict__ we, const float* __restrict__ pe, float* __restrict__ x) {
  int i = blockIdx.x * 256 + threadIdx.x;
  int n = i >> 10;
  int d = i & 1023;
  int t = n & (TSEQ - 1);
  x[i] = we[(size_t)idx[n] * DM + d] + pe[(size_t)t * DM + d];
}

// ---------------- LayerNorm -> bf16 out -------------------------------------
__global__ __launch_bounds__(256) void ln_bf(const float* __restrict__ in,
    const float* __restrict__ g, const float* __restrict__ b,
    short* __restrict__ outb) {
  __shared__ float sh[4];
  int row = blockIdx.x, tid = threadIdx.x;
  const float* xr = in + (size_t)row * DM;
  float4 v = *(const float4*)&xr[tid * 4];
  float s  = v.x + v.y + v.z + v.w;
  float s2 = v.x*v.x + v.y*v.y + v.z*v.z + v.w*v.w;
  s  = block_sum256(s, sh);
  s2 = block_sum256(s2, sh);
  float mean = s * (1.0f / DM);
  float var  = s2 * (1.0f / DM) - mean * mean;
  float inv  = rsqrtf(var + 1e-5f);
  float4 gv = *(const float4*)&g[tid * 4];
  float4 bv = *(const float4*)&b[tid * 4];
  float4 o;
  o.x = (v.x - mean) * inv * gv.x + bv.x;
  o.y = (v.y - mean) * inv * gv.y + bv.y;
  o.z = (v.z - mean) * inv * gv.z + bv.z;
  o.w = (v.w - mean) * inv * gv.w + bv.w;
  short4v ob;
  ob.x = f2bf(o.x); ob.y = f2bf(o.y); ob.z = f2bf(o.z); ob.w = f2bf(o.w);
  *(short4v*)&outb[(size_t)row * DM + tid * 4] = ob;
}

// ---------------- final LN -> xf_bf + probs (log_softmax over D) ------------
__global__ __launch_bounds__(256) void ln_probs(const float* __restrict__ in,
    const float* __restrict__ g, const float* __restrict__ b,
    short* __restrict__ outb, float* __restrict__ probs) {
  __shared__ float sh[4];
  int row = blockIdx.x, tid = threadIdx.x;
  const float* xr = in + (size_t)row * DM;
  float4 v = *(const float4*)&xr[tid * 4];
  float s  = v.x + v.y + v.z + v.w;
  float s2 = v.x*v.x + v.y*v.y + v.z*v.z + v.w*v.w;
  s  = block_sum256(s, sh);
  s2 = block_sum256(s2, sh);
  float mean = s * (1.0f / DM);
  float var  = s2 * (1.0f / DM) - mean * mean;
  float inv  = rsqrtf(var + 1e-5f);
  float4 gv = *(const float4*)&g[tid * 4];
  float4 bv = *(const float4*)&b[tid * 4];
  float4 o;
  o.x = (v.x - mean) * inv * gv.x + bv.x;
  o.y = (v.y - mean) * inv * gv.y + bv.y;
  o.z = (v.z - mean) * inv * gv.z + bv.z;
  o.w = (v.w - mean) * inv * gv.w + bv.w;
  short4v ob;
  ob.x = f2bf(o.x); ob.y = f2bf(o.y); ob.z = f2bf(o.z); ob.w = f2bf(o.w);
  *(short4v*)&outb[(size_t)row * DM + tid * 4] = ob;
  float m = block_max256(fmaxf(fmaxf(o.x, o.y), fmaxf(o.z, o.w)), sh);
  float ssum = __expf(o.x-m) + __expf(o.y-m) + __expf(o.z-m) + __expf(o.w-m);
  ssum = block_sum256(ssum, sh);
  float lg = m + logf(ssum);
  float* orow = probs + (size_t)row * DM + tid * 4;  // 4B-aligned only
  orow[0] = o.x - lg;
  orow[1] = o.y - lg;
  orow[2] = o.z - lg;
  orow[3] = o.w - lg;
}

// ---------------- bf16 x bf16 MFMA GEMM, global_load_lds staging ------------
// LOSSP: epilogue writes per-row partial sum(exp(val)) for this 128-col block.
// SWZ: 1D grid + XCD-bijective swizzle (gridDim.x % 8 == 0 required).
template<int BIAS, int RES, int RELU, int OUTBF, int LOSSP, int SWZ>
__global__ __launch_bounds__(256) void gemm_bb(const short* __restrict__ A, int lda,
    const short* __restrict__ Bt, const float* __restrict__ bias,
    void* __restrict__ Cv, int M, int K, int Nn,
    float* __restrict__ lpart, int mblocks) {
  __shared__ short As[128 * 32];
  __shared__ short Bs[128 * 32];
  float* Cf = (float*)Cv;
  short* Cb = (short*)Cv;
  const int tid  = threadIdx.x;
  int bm, bn;
  if (SWZ) {
    const int cpx = gridDim.x >> 3;
    const int swz = (blockIdx.x & 7) * cpx + (blockIdx.x >> 3);
    bm = (swz % mblocks) * 128;
    bn = (swz / mblocks) * 128;
  } else {
    bm = blockIdx.x * 128; bn = blockIdx.y * 128;
  }
  const int lane = tid & 63, wid = tid >> 6;
  const int wr = wid >> 1, wc = wid & 1;
  const int lr = lane & 15, lg = lane >> 4;
  const int srow = lane >> 2;
  const int schunk = (lane & 3) * 8;

  f32x4 acc[4][4];
#pragma unroll
  for (int i = 0; i < 4; ++i)
#pragma unroll
    for (int j = 0; j < 4; ++j) acc[i][j] = (f32x4)0.f;

  for (int k0 = 0; k0 < K; k0 += 32) {
#pragma unroll
    for (int t = 0; t < 2; ++t) {
      const int issue = wid * 2 + t;
      const int row = issue * 16 + srow;
      gload16(&A[(size_t)(bm + row) * lda + k0 + schunk], &As[issue * 512]);
      gload16(&Bt[(size_t)(bn + row) * K  + k0 + schunk], &Bs[issue * 512]);
    }
    __syncthreads();
    bf8 af[4], bfv[4];
#pragma unroll
    for (int i = 0; i < 4; ++i)
      af[i] = *(const bf8*)&As[(wr * 64 + i * 16 + lr) * 32 + lg * 8];
#pragma unroll
    for (int j = 0; j < 4; ++j)
      bfv[j] = *(const bf8*)&Bs[(wc * 64 + j * 16 + lr) * 32 + lg * 8];
#pragma unroll
    for (int i = 0; i < 4; ++i)
#pragma unroll
      for (int j = 0; j < 4; ++j)
        acc[i][j] = __builtin_amdgcn_mfma_f32_16x16x32_bf16(af[i], bfv[j], acc[i][j], 0, 0, 0);
    __syncthreads();
  }
  float* Ls = (float*)As;   // reused after last barrier
#pragma unroll
  for (int i = 0; i < 4; ++i) {
#pragma unroll
    for (int v = 0; v < 4; ++v) {
      int rl = wr * 64 + i * 16 + lg * 4 + v;
      size_t rowb = (size_t)(bm + rl) * Nn;
      float pe = 0.f;
#pragma unroll
      for (int j = 0; j < 4; ++j) {
        int col = bn + wc * 64 + j * 16 + lr;
        float val = acc[i][j][v];
        if (BIAS) val += bias[col];
        if (RES)  val += Cf[rowb + col];
        if (RELU) val = fmaxf(val, 0.f);
        if (OUTBF) Cb[rowb + col] = f2bf(val);
        else       Cf[rowb + col] = val;
        if (LOSSP) pe += __expf(val);
      }
      if (LOSSP) {
#pragma unroll
        for (int off = 8; off; off >>= 1) pe += __shfl_xor(pe, off);
        if (lr == 0) Ls[rl * 2 + wc] = pe;
      }
    }
  }
  if (LOSSP) {
    __syncthreads();
    if (tid < 128)
      lpart[(size_t)(bm + tid) * 256 + (bn >> 7)] = Ls[tid * 2] + Ls[tid * 2 + 1];
  }
}

// ---------------- lm_head fallback: bf16 A copy + f32 B on-the-fly cvt ------
template<int BIAS, int LOSSP, int SWZ>
__global__ __launch_bounds__(256) void gemm_lm_cvt(const short* __restrict__ A,
    const float* __restrict__ Bw, const float* __restrict__ bias,
    float* __restrict__ C, int M, int K, int Nn,
    float* __restrict__ lpart, int mblocks) {
  __shared__ short As[128 * 40];
  __shared__ short Bs[128 * 40];
  const int tid  = threadIdx.x;
  int bm, bn;
  if (SWZ) {
    const int cpx = gridDim.x >> 3;
    const int swz = (blockIdx.x & 7) * cpx + (blockIdx.x >> 3);
    bm = (swz % mblocks) * 128;
    bn = (swz / mblocks) * 128;
  } else {
    bm = blockIdx.x * 128; bn = blockIdx.y * 128;
  }
  const int lane = tid & 63, wid = tid >> 6;
  const int wr = wid >> 1, wc = wid & 1;
  const int lr = lane & 15, lg = lane >> 4;
  const int sr = tid >> 1, sh2 = (tid & 1) * 16;
  const int sbn = tid & 127, sbk = (tid >> 7) * 16;
  f32x4 acc[4][4];
#pragma unroll
  for (int i = 0; i < 4; ++i)
#pragma unroll
    for (int j = 0; j < 4; ++j) acc[i][j] = (f32x4)0.f;
  for (int k0 = 0; k0 < K; k0 += 32) {
    {
      const short* asrc = &A[(size_t)(bm + sr) * K + k0 + sh2];
      *(bf8*)&As[sr * 40 + sh2    ] = *(const bf8*)&asrc[0];
      *(bf8*)&As[sr * 40 + sh2 + 8] = *(const bf8*)&asrc[8];
    }
    {
      short tmp[16];
#pragma unroll
      for (int e = 0; e < 16; ++e)
        tmp[e] = f2bf(Bw[(size_t)(k0 + sbk + e) * Nn + bn + sbn]);
      *(bf8*)&Bs[sbn * 40 + sbk    ] = *(bf8*)&tmp[0];
      *(bf8*)&Bs[sbn * 40 + sbk + 8] = *(bf8*)&tmp[8];
    }
    __syncthreads();
    bf8 af[4], bfv[4];
#pragma unroll
    for (int i = 0; i < 4; ++i)
      af[i] = *(const bf8*)&As[(wr * 64 + i * 16 + lr) * 40 + lg * 8];
#pragma unroll
    for (int j = 0; j < 4; ++j)
      bfv[j] = *(const bf8*)&Bs[(wc * 64 + j * 16 + lr) * 40 + lg * 8];
#pragma unroll
    for (int i = 0; i < 4; ++i)
#pragma unroll
      for (int j = 0; j < 4; ++j)
        acc[i][j] = __builtin_amdgcn_mfma_f32_16x16x32_bf16(af[i], bfv[j], acc[i][j], 0, 0, 0);
    __syncthreads();
  }
  float* Ls = (float*)As;
#pragma unroll
  for (int i = 0; i < 4; ++i) {
#pragma unroll
    for (int v = 0; v < 4; ++v) {
      int rl = wr * 64 + i * 16 + lg * 4 + v;
      size_t rowb = (size_t)(bm + rl) * Nn;
      float pe = 0.f;
#pragma unroll
      for (int j = 0; j < 4; ++j) {
        int col = bn + wc * 64 + j * 16 + lr;
        float val = acc[i][j][v];
        if (BIAS) val += bias[col];
        C[rowb + col] = val;
        if (LOSSP) pe += __expf(val);
      }
      if (LOSSP) {
#pragma unroll
        for (int off = 8; off; off >>= 1) pe += __shfl_xor(pe, off);
        if (lr == 0) Ls[rl * 2 + wc] = pe;
      }
    }
  }
  if (LOSSP) {
    __syncthreads();
    if (tid < 128)
      lpart[(size_t)(bm + tid) * 256 + (bn >> 7)] = Ls[tid * 2] + Ls[tid * 2 + 1];
  }
}

// ---------------- fused QK^T + causal softmax + PV --------------------------
// Phase 1: MFMA QK^T into LDS strip S[QT][1024]. Phase 2: row softmax (P kept
// in S). Phase 3: COALESCED maps write (float4/thread, zeros past diagonal).
// Phase 4: PV -- stage V 64-row tiles into Ks (reuse), accumulate; write bf16.
__global__ __launch_bounds__(256) void attn_fused(const short* __restrict__ qkv_bf,
    float* __restrict__ maps_l, short* __restrict__ att_bf) {
  __shared__ float S[QT][1032];
  __shared__ short Qs[QT * 72];
  __shared__ short Ks[64 * 72];
  const int tid = threadIdx.x;
  const int q0 = blockIdx.x * QT;
  const int bh = blockIdx.y;
  const int b = bh >> 4, h = bh & 15;
  const int lane = tid & 63, wid = tid >> 6;
  const int lr = lane & 15, lg = lane >> 4;
  if (tid < 128) {                       // stage Q: 16 rows x 64 bf16
    int r = tid >> 3, c8 = (tid & 7) * 8;
    *(bf8*)&Qs[r * 72 + c8] =
      *(const bf8*)&qkv_bf[(size_t)(b * TSEQ + q0 + r) * 3072 + h * 64 + c8];
  }
  const int ktmax = (q0 + QT - 1) / 64 + 1;
  for (int kt = 0; kt < ktmax; ++kt) {
    const int k0 = kt * 64;
    {                                    // stage K tile: 64 rows x 64 bf16
      int r = tid >> 2, c16 = (tid & 3) * 16;
      const short* src = &qkv_bf[(size_t)(b * TSEQ + k0 + r) * 3072 + 1024 + h * 64 + c16];
      *(bf8*)&Ks[r * 72 + c16    ] = *(const bf8*)&src[0];
      *(bf8*)&Ks[r * 72 + c16 + 8] = *(const bf8*)&src[8];
    }
    __syncthreads();
    f32x4 acc = (f32x4)0.f;
#pragma unroll
    for (int ds = 0; ds < 2; ++ds) {
      bf8 af  = *(const bf8*)&Qs[lr * 72 + ds * 32 + lg * 8];
      bf8 bfv = *(const bf8*)&Ks[(wid * 16 + lr) * 72 + ds * 32 + lg * 8];
      acc = __builtin_amdgcn_mfma_f32_16x16x32_bf16(af, bfv, acc, 0, 0, 0);
    }
#pragma unroll
    for (int v = 0; v < 4; ++v)
      S[lg * 4 + v][k0 + wid * 16 + lr] = acc[v] * 0.03125f;
    __syncthreads();
  }
  // row softmax: 16 rows x 16 threads each; P kept in S (no global write)
  const int r = tid >> 4, l16 = tid & 15;
  const int qg = q0 + r;                 // valid cols 0..qg
  float m = -1e30f;
  for (int c = l16; c <= qg; c += 16) m = fmaxf(m, S[r][c]);
#pragma unroll
  for (int off = 8; off; off >>= 1) m = fmaxf(m, __shfl_xor(m, off, 16));
  float ssum = 0.f;
  for (int c = l16; c <= qg; c += 16) ssum += __expf(S[r][c] - m);
#pragma unroll
  for (int off = 8; off; off >>= 1) ssum += __shfl_xor(ssum, off, 16);
  const float inv = 1.f / ssum;
  for (int c = l16; c <= qg; c += 16)
    S[r][c] = __expf(S[r][c] - m) * inv;
  __syncthreads();
  // coalesced maps write: 16 rows x (256 threads x float4)
  const int c4 = tid * 4;
#pragma unroll 4
  for (int rr = 0; rr < QT; ++rr) {
    const int qgr = q0 + rr;
    float4 p4;
    p4.x = (c4     <= qgr) ? S[rr][c4    ] : 0.f;
    p4.y = (c4 + 1 <= qgr) ? S[rr][c4 + 1] : 0.f;
    p4.z = (c4 + 2 <= qgr) ? S[rr][c4 + 2] : 0.f;
    p4.w = (c4 + 3 <= qgr) ? S[rr][c4 + 3] : 0.f;
    *(float4*)&maps_l[(size_t)bh * TSEQ * TSEQ + (size_t)qgr * TSEQ + c4] = p4;
  }
  __syncthreads();
  // PV: thread (r,l16) owns d = l16*4..+3; V tiles staged into Ks (reuse)
  const int dbase = l16 * 4;
  float4 a = {0.f, 0.f, 0.f, 0.f};
  for (int kt = 0; kt < ktmax; ++kt) {
    const int k0 = kt * 64;
    {
      int vr2 = tid >> 2, vc2 = (tid & 3) * 16;
      const short* src = &qkv_bf[(size_t)(b * TSEQ + k0 + vr2) * 3072 + 2048 + h * 64 + vc2];
      *(bf8*)&Ks[vr2 * 72 + vc2    ] = *(const bf8*)&src[0];
      *(bf8*)&Ks[vr2 * 72 + vc2 + 8] = *(const bf8*)&src[8];
    }
    __syncthreads();
    int kend = qg - k0 + 1;
    if (kend > 64) kend = 64;
    if (kend < 0) kend = 0;
#pragma unroll 4
    for (int k = 0; k < kend; ++k) {
      float p = S[r][k0 + k];
      short4v vv = *(const short4v*)&Ks[k * 72 + dbase];
      a.x += p * bf2f(vv.x); a.y += p * bf2f(vv.y);
      a.z += p * bf2f(vv.z); a.w += p * bf2f(vv.w);
    }
    __syncthreads();
  }
  short* orow = &att_bf[(size_t)(b * TSEQ + qg) * DM + h * 64 + dbase];
  short4v s0;
  s0.x = f2bf(a.x); s0.y = f2bf(a.y); s0.z = f2bf(a.z); s0.w = f2bf(a.w);
  *(short4v*)orow = s0;
}

// ---------------- loss: combine partials; mean-reduce ------------------------
__global__ __launch_bounds__(256) void loss_final(const float* __restrict__ lpart,
    const float* __restrict__ logits, const int* __restrict__ targets,
    float* __restrict__ rowloss) {
  __shared__ float sh[4];
  int row = blockIdx.x, tid = threadIdx.x;
  float s = (tid < VSZ / 128) ? lpart[(size_t)row * 256 + tid] : 0.f;
  s = block_sum256(s, sh);
  if (tid == 0)
    rowloss[row] = logf(s) - logits[(size_t)row * VSZ + targets[row]];
}
__global__ __launch_bounds__(256) void loss_reduce(const float* __restrict__ rowloss,
    float* __restrict__ out) {
  __shared__ float sh[4];
  float s = 0.f;
  for (int i = threadIdx.x; i < NTOK; i += 256) s += rowloss[i];
  s = block_sum256(s, sh);
  if (threadIdx.x == 0) out[0] = s * (1.0f / NTOK);
}

// ============================================================================
extern "C" void kernel_launch(void* const* d_in, const int* in_sizes, int n_in,
                              void* d_out, int out_size, void* d_ws, size_t ws_size,
                              hipStream_t stream) {
  const int*   idx      = (const int*)  d_in[0];
  const int*   targets  = (const int*)  d_in[1];
  const float* word_emb = (const float*)d_in[2];
  const float* pos_emb  = (const float*)d_in[3];
  const float* ln1_g    = (const float*)d_in[4];
  const float* ln1_b    = (const float*)d_in[5];
  const float* wq       = (const float*)d_in[6];
  const float* wk       = (const float*)d_in[7];
  const float* wv       = (const float*)d_in[8];
  const float* proj_w   = (const float*)d_in[9];
  const float* proj_b   = (const float*)d_in[10];
  const float* ln2_g    = (const float*)d_in[11];
  const float* ln2_b    = (const float*)d_in[12];
  const float* ff_w1    = (const float*)d_in[13];
  const float* ff_b1    = (const float*)d_in[14];
  const float* ff_w2    = (const float*)d_in[15];
  const float* ff_b2    = (const float*)d_in[16];
  const float* lnf_g    = (const float*)d_in[17];
  const float* lnf_b    = (const float*)d_in[18];
  const float* lm_w     = (const float*)d_in[19];
  const float* lm_b     = (const float*)d_in[20];

  float* outf   = (float*)d_out;
  float* logits = outf + LOGITS_OFF;
  float* lossp  = outf + LOSS_OFF;
  float* maps   = outf + MAPS_OFF;
  float* probs  = outf + PROBS_OFF;

  const size_t ND = (size_t)NTOK * DM;
  // ---- activation scratch in d_ws (~52 MB) ----
  float* x    = (float*)d_ws;                 // ND f32
  float* rowloss = x + ND;                    // NTOK f32
  float* lpart   = rowloss + NTOK;            // NTOK*256 f32 (2 MB)
  short* qkv_bf = (short*)(lpart + (size_t)NTOK * 256);  // 3*ND bf16
  short* h_bf   = qkv_bf + 3 * ND;            // ND bf16
  short* att_bf = h_bf + ND;                  // ND bf16
  short* ffh_bf = att_bf + ND;                // NTOK*FFD bf16
  short* xf_bf  = ffh_bf + (size_t)NTOK * FFD;// ND bf16
  char*  ws_end = (char*)(xf_bf + ND);
  const size_t act_bytes = (size_t)(ws_end - (char*)d_ws);
  const size_t lmwt_bytes = (size_t)VSZ * DM * sizeof(short);
  const int lm_fast = (ws_size >= act_bytes + lmwt_bytes);
  short* lm_wt = (short*)ws_end;

  short* wt_base = (short*)logits;            // bf16 layer weights in logits slot
  auto layer_wt = [&](int l) { return wt_base + (size_t)l * PLW; };

  dim3 b256(256);
  transpose_all<<<dim3(2 * 3072), b256, 0, stream>>>(wq, wk, wv, proj_w, ff_w1, ff_w2, wt_base);
  if (lm_fast)
    transpose_cvt<<<dim3(VSZ/64, 16), b256, 0, stream>>>(lm_w, lm_wt, DM, VSZ);

  embed_kernel<<<dim3((NTOK * DM) / 256), b256, 0, stream>>>(idx, word_emb, pos_emb, x);

  const int mb = NTOK / 128;                  // 16
  for (int l = 0; l < LL; ++l) {
    short* qkvt = layer_wt(l);
    short* projt = qkvt + (size_t)3 * DM * DM;
    short* ff1t  = projt + (size_t)DM * DM;
    short* ff2t  = ff1t + (size_t)DM * FFD;
    ln_bf<<<dim3(NTOK), b256, 0, stream>>>(x, ln1_g + l * DM, ln1_b + l * DM, h_bf);
    gemm_bb<0,0,0,1,0,1><<<dim3(mb * (3072/128)), b256, 0, stream>>>(h_bf, DM, qkvt, nullptr, qkv_bf, NTOK, DM, 3072, nullptr, mb);
    float* maps_l = maps + (size_t)l * BB * HH * TSEQ * TSEQ;
    attn_fused<<<dim3(TSEQ/QT, BB*HH), b256, 0, stream>>>(qkv_bf, maps_l, att_bf);
    gemm_bb<1,1,0,0,0,1><<<dim3(mb * (DM/128)), b256, 0, stream>>>(att_bf, DM, projt, proj_b + l * DM, x, NTOK, DM, DM, nullptr, mb);
    ln_bf<<<dim3(NTOK), b256, 0, stream>>>(x, ln2_g + l * DM, ln2_b + l * DM, h_bf);
    gemm_bb<1,0,1,1,0,1><<<dim3(mb * (FFD/128)), b256, 0, stream>>>(h_bf, DM, ff1t, ff_b1 + l * FFD, ffh_bf, NTOK, DM, FFD, nullptr, mb);
    gemm_bb<1,1,0,0,0,1><<<dim3(mb * (DM/128)), b256, 0, stream>>>(ffh_bf, FFD, ff2t, ff_b2 + l * DM, x, NTOK, FFD, DM, nullptr, mb);
  }

  ln_probs<<<dim3(NTOK), b256, 0, stream>>>(x, lnf_g, lnf_b, xf_bf, probs);
  const int nwg_lm = mb * (VSZ / 128);        // 4000 (divisible by 8)
  if (lm_fast)
    gemm_bb<1,0,0,0,1,1><<<dim3(nwg_lm), b256, 0, stream>>>(xf_bf, DM, lm_wt, lm_b, logits, NTOK, DM, VSZ, lpart, mb);
  else
    gemm_lm_cvt<1,1,1><<<dim3(nwg_lm), b256, 0, stream>>>(xf_bf, lm_w, lm_b, logits, NTOK, DM, VSZ, lpart, mb);
  loss_final<<<dim3(NTOK), b256, 0, stream>>>(lpart, logits, targets, rowloss);
  loss_reduce<<<dim3(1), b256, 0, stream>>>(rowloss, lossp);

  (void)in_sizes; (void)n_in; (void)out_size;
}

// Round 14
// 1152.855 us; speedup vs baseline: 1.0228x; 1.0228x over previous
//
#include <hip/hip_runtime.h>
#include <hip/hip_bf16.h>

// Decoder forward: B=2,T=1024,D=1024,H=16(hs=64),L=2,FF=4096,V=32000
// Outputs (f32, concat): logits[N,V], loss[1], maps[L,B,H,T,T], probs[N,D]
// Round 14: revert XCD swizzle (L3-fit data -> swizzle costs, per guide m160);
// keep coalesced maps write; lm_w transpose folded into transpose_all.
#define VSZ 32000
#define DM  1024
#define TSEQ 1024
#define BB  2
#define HH  16
#define LL  2
#define FFD 4096
#define NTOK (BB*TSEQ)   // 2048
#define QT  16           // q-rows per attn_fused block

static constexpr size_t LOGITS_OFF = 0;
static constexpr size_t LOSS_OFF   = (size_t)NTOK * VSZ;
static constexpr size_t MAPS_OFF   = LOSS_OFF + 1;
static constexpr size_t PROBS_OFF  = MAPS_OFF + (size_t)LL*BB*HH*TSEQ*TSEQ;

typedef __attribute__((ext_vector_type(8))) short bf8;
typedef __attribute__((ext_vector_type(4))) float f32x4;
typedef __attribute__((ext_vector_type(4))) short short4v;

__device__ __forceinline__ short f2bf(float f) {   // RTNE f32 -> bf16 bits
  union { float f; unsigned u; } v; v.f = f;
  unsigned r = v.u + 0x7FFFu + ((v.u >> 16) & 1u);
  return (short)(r >> 16);
}
__device__ __forceinline__ float bf2f(short s) {
  union { unsigned u; float f; } v; v.u = ((unsigned)(unsigned short)s) << 16;
  return v.f;
}

// Async global->LDS, 16 B/lane (dest = wave-uniform base + lane*16).
__device__ __forceinline__ void gload16(const void* g, void* l) {
  __builtin_amdgcn_global_load_lds(
      (const __attribute__((address_space(1))) void*)g,
      (__attribute__((address_space(3))) void*)l, 16, 0, 0);
}

// ---------------- reductions ----------------
__device__ __forceinline__ float block_sum256(float v, float* sh) {
#pragma unroll
  for (int off = 32; off; off >>= 1) v += __shfl_down(v, off);
  int wid = threadIdx.x >> 6, lane = threadIdx.x & 63;
  if (lane == 0) sh[wid] = v;
  __syncthreads();
  v = sh[0] + sh[1] + sh[2] + sh[3];
  __syncthreads();
  return v;
}
__device__ __forceinline__ float block_max256(float v, float* sh) {
#pragma unroll
  for (int off = 32; off; off >>= 1) v = fmaxf(v, __shfl_down(v, off));
  int wid = threadIdx.x >> 6, lane = threadIdx.x & 63;
  if (lane == 0) sh[wid] = v;
  __syncthreads();
  v = fmaxf(fmaxf(sh[0], sh[1]), fmaxf(sh[2], sh[3]));
  __syncthreads();
  return v;
}

// ---------------- fused weight transpose+convert (layer weights + lm_w) -----
// W[K][N] f32 -> Wt[N][K] bf16. 64x64 tiles.
// Blocks [0, 6144): layer weights (3072/layer); blocks >= 6144: lm_w tiles.
static constexpr size_t PLW = (size_t)4 * DM * DM + (size_t)DM * FFD + (size_t)FFD * DM;
__global__ __launch_bounds__(256) void transpose_all(const float* __restrict__ wq,
    const float* __restrict__ wk, const float* __restrict__ wv,
    const float* __restrict__ proj_w, const float* __restrict__ ff_w1,
    const float* __restrict__ ff_w2, short* __restrict__ wt_base,
    const float* __restrict__ lm_w, short* __restrict__ lm_wt) {
  __shared__ float T[64][65];
  const int bid = blockIdx.x;
  const float* W; short* Wt; int K, N, tn, tk;
  if (bid < 2 * 3072) {
    const int l = bid / 3072, r = bid % 3072;
    short* qbase = wt_base + (size_t)l * PLW;
    if (r < 1024) {
      int s = r >> 8, rr = r & 255;
      W = (s == 0 ? wq : (s == 1 ? wk : (s == 2 ? wv : proj_w))) + (size_t)l * DM * DM;
      Wt = qbase + (size_t)s * DM * DM;
      K = DM; N = DM; tn = rr & 15; tk = rr >> 4;
    } else if (r < 2048) {
      int rr = r - 1024;
      W = ff_w1 + (size_t)l * DM * FFD; Wt = qbase + (size_t)4 * DM * DM;
      K = DM; N = FFD; tn = rr & 63; tk = rr >> 6;
    } else {
      int rr = r - 2048;
      W = ff_w2 + (size_t)l * FFD * DM; Wt = qbase + (size_t)4 * DM * DM + (size_t)DM * FFD;
      K = FFD; N = DM; tn = rr & 15; tk = rr >> 4;
    }
  } else {
    const int r2 = bid - 2 * 3072;         // 0..7999
    W = lm_w; Wt = lm_wt;
    K = DM; N = VSZ; tn = r2 % 500; tk = r2 / 500;
  }
  const int n0 = tn * 64, k0 = tk * 64;
  const int tid = threadIdx.x;
  const int lr = tid >> 4, lc4 = (tid & 15) * 4;
#pragma unroll
  for (int p = 0; p < 4; ++p) {
    int k = lr + p * 16;
    float4 w = *(const float4*)&W[(size_t)(k0 + k) * N + n0 + lc4];
    T[k][lc4] = w.x; T[k][lc4+1] = w.y; T[k][lc4+2] = w.z; T[k][lc4+3] = w.w;
  }
  __syncthreads();
#pragma unroll
  for (int p = 0; p < 4; ++p) {
    int n = lr + p * 16;
    short4v s;
    s.x = f2bf(T[lc4  ][n]);
    s.y = f2bf(T[lc4+1][n]);
    s.z = f2bf(T[lc4+2][n]);
    s.w = f2bf(T[lc4+3][n]);
    *(short4v*)&Wt[(size_t)(n0 + n) * K + k0 + lc4] = s;
  }
}

// ---------------- embedding ----------------
__global__ __launch_bounds__(256) void embed_kernel(const int* __restrict__ idx,
    const float* __restrict__ we, const float* __restrict__ pe, float* __restrict__ x) {
  int i = blockIdx.x * 256 + threadIdx.x;
  int n = i >> 10;
  int d = i & 1023;
  int t = n & (TSEQ - 1);
  x[i] = we[(size_t)idx[n] * DM + d] + pe[(size_t)t * DM + d];
}

// ---------------- LayerNorm -> bf16 out -------------------------------------
__global__ __launch_bounds__(256) void ln_bf(const float* __restrict__ in,
    const float* __restrict__ g, const float* __restrict__ b,
    short* __restrict__ outb) {
  __shared__ float sh[4];
  int row = blockIdx.x, tid = threadIdx.x;
  const float* xr = in + (size_t)row * DM;
  float4 v = *(const float4*)&xr[tid * 4];
  float s  = v.x + v.y + v.z + v.w;
  float s2 = v.x*v.x + v.y*v.y + v.z*v.z + v.w*v.w;
  s  = block_sum256(s, sh);
  s2 = block_sum256(s2, sh);
  float mean = s * (1.0f / DM);
  float var  = s2 * (1.0f / DM) - mean * mean;
  float inv  = rsqrtf(var + 1e-5f);
  float4 gv = *(const float4*)&g[tid * 4];
  float4 bv = *(const float4*)&b[tid * 4];
  float4 o;
  o.x = (v.x - mean) * inv * gv.x + bv.x;
  o.y = (v.y - mean) * inv * gv.y + bv.y;
  o.z = (v.z - mean) * inv * gv.z + bv.z;
  o.w = (v.w - mean) * inv * gv.w + bv.w;
  short4v ob;
  ob.x = f2bf(o.x); ob.y = f2bf(o.y); ob.z = f2bf(o.z); ob.w = f2bf(o.w);
  *(short4v*)&outb[(size_t)row * DM + tid * 4] = ob;
}

// ---------------- final LN -> xf_bf + probs (log_softmax over D) ------------
__global__ __launch_bounds__(256) void ln_probs(const float* __restrict__ in,
    const float* __restrict__ g, const float* __restrict__ b,
    short* __restrict__ outb, float* __restrict__ probs) {
  __shared__ float sh[4];
  int row = blockIdx.x, tid = threadIdx.x;
  const float* xr = in + (size_t)row * DM;
  float4 v = *(const float4*)&xr[tid * 4];
  float s  = v.x + v.y + v.z + v.w;
  float s2 = v.x*v.x + v.y*v.y + v.z*v.z + v.w*v.w;
  s  = block_sum256(s, sh);
  s2 = block_sum256(s2, sh);
  float mean = s * (1.0f / DM);
  float var  = s2 * (1.0f / DM) - mean * mean;
  float inv  = rsqrtf(var + 1e-5f);
  float4 gv = *(const float4*)&g[tid * 4];
  float4 bv = *(const float4*)&b[tid * 4];
  float4 o;
  o.x = (v.x - mean) * inv * gv.x + bv.x;
  o.y = (v.y - mean) * inv * gv.y + bv.y;
  o.z = (v.z - mean) * inv * gv.z + bv.z;
  o.w = (v.w - mean) * inv * gv.w + bv.w;
  short4v ob;
  ob.x = f2bf(o.x); ob.y = f2bf(o.y); ob.z = f2bf(o.z); ob.w = f2bf(o.w);
  *(short4v*)&outb[(size_t)row * DM + tid * 4] = ob;
  float m = block_max256(fmaxf(fmaxf(o.x, o.y), fmaxf(o.z, o.w)), sh);
  float ssum = __expf(o.x-m) + __expf(o.y-m) + __expf(o.z-m) + __expf(o.w-m);
  ssum = block_sum256(ssum, sh);
  float lg = m + logf(ssum);
  float* orow = probs + (size_t)row * DM + tid * 4;  // 4B-aligned only
  orow[0] = o.x - lg;
  orow[1] = o.y - lg;
  orow[2] = o.z - lg;
  orow[3] = o.w - lg;
}

// ---------------- bf16 x bf16 MFMA GEMM, global_load_lds staging ------------
// LOSSP: epilogue writes per-row partial sum(exp(val)) for this 128-col block.
template<int BIAS, int RES, int RELU, int OUTBF, int LOSSP>
__global__ __launch_bounds__(256) void gemm_bb(const short* __restrict__ A, int lda,
    const short* __restrict__ Bt, const float* __restrict__ bias,
    void* __restrict__ Cv, int M, int K, int Nn,
    float* __restrict__ lpart) {
  __shared__ short As[128 * 32];
  __shared__ short Bs[128 * 32];
  float* Cf = (float*)Cv;
  short* Cb = (short*)Cv;
  const int tid  = threadIdx.x;
  const int bm = blockIdx.x * 128, bn = blockIdx.y * 128;
  const int lane = tid & 63, wid = tid >> 6;
  const int wr = wid >> 1, wc = wid & 1;
  const int lr = lane & 15, lg = lane >> 4;
  const int srow = lane >> 2;
  const int schunk = (lane & 3) * 8;

  f32x4 acc[4][4];
#pragma unroll
  for (int i = 0; i < 4; ++i)
#pragma unroll
    for (int j = 0; j < 4; ++j) acc[i][j] = (f32x4)0.f;

  for (int k0 = 0; k0 < K; k0 += 32) {
#pragma unroll
    for (int t = 0; t < 2; ++t) {
      const int issue = wid * 2 + t;
      const int row = issue * 16 + srow;
      gload16(&A[(size_t)(bm + row) * lda + k0 + schunk], &As[issue * 512]);
      gload16(&Bt[(size_t)(bn + row) * K  + k0 + schunk], &Bs[issue * 512]);
    }
    __syncthreads();
    bf8 af[4], bfv[4];
#pragma unroll
    for (int i = 0; i < 4; ++i)
      af[i] = *(const bf8*)&As[(wr * 64 + i * 16 + lr) * 32 + lg * 8];
#pragma unroll
    for (int j = 0; j < 4; ++j)
      bfv[j] = *(const bf8*)&Bs[(wc * 64 + j * 16 + lr) * 32 + lg * 8];
#pragma unroll
    for (int i = 0; i < 4; ++i)
#pragma unroll
      for (int j = 0; j < 4; ++j)
        acc[i][j] = __builtin_amdgcn_mfma_f32_16x16x32_bf16(af[i], bfv[j], acc[i][j], 0, 0, 0);
    __syncthreads();
  }
  float* Ls = (float*)As;   // reused after last barrier
#pragma unroll
  for (int i = 0; i < 4; ++i) {
#pragma unroll
    for (int v = 0; v < 4; ++v) {
      int rl = wr * 64 + i * 16 + lg * 4 + v;
      size_t rowb = (size_t)(bm + rl) * Nn;
      float pe = 0.f;
#pragma unroll
      for (int j = 0; j < 4; ++j) {
        int col = bn + wc * 64 + j * 16 + lr;
        float val = acc[i][j][v];
        if (BIAS) val += bias[col];
        if (RES)  val += Cf[rowb + col];
        if (RELU) val = fmaxf(val, 0.f);
        if (OUTBF) Cb[rowb + col] = f2bf(val);
        else       Cf[rowb + col] = val;
        if (LOSSP) pe += __expf(val);
      }
      if (LOSSP) {
#pragma unroll
        for (int off = 8; off; off >>= 1) pe += __shfl_xor(pe, off);
        if (lr == 0) Ls[rl * 2 + wc] = pe;
      }
    }
  }
  if (LOSSP) {
    __syncthreads();
    if (tid < 128)
      lpart[(size_t)(bm + tid) * 256 + (bn >> 7)] = Ls[tid * 2] + Ls[tid * 2 + 1];
  }
}

// ---------------- lm_head fallback: bf16 A copy + f32 B on-the-fly cvt ------
template<int BIAS, int LOSSP>
__global__ __launch_bounds__(256) void gemm_lm_cvt(const short* __restrict__ A,
    const float* __restrict__ Bw, const float* __restrict__ bias,
    float* __restrict__ C, int M, int K, int Nn,
    float* __restrict__ lpart) {
  __shared__ short As[128 * 40];
  __shared__ short Bs[128 * 40];
  const int tid  = threadIdx.x;
  const int bm = blockIdx.x * 128, bn = blockIdx.y * 128;
  const int lane = tid & 63, wid = tid >> 6;
  const int wr = wid >> 1, wc = wid & 1;
  const int lr = lane & 15, lg = lane >> 4;
  const int sr = tid >> 1, sh2 = (tid & 1) * 16;
  const int sbn = tid & 127, sbk = (tid >> 7) * 16;
  f32x4 acc[4][4];
#pragma unroll
  for (int i = 0; i < 4; ++i)
#pragma unroll
    for (int j = 0; j < 4; ++j) acc[i][j] = (f32x4)0.f;
  for (int k0 = 0; k0 < K; k0 += 32) {
    {
      const short* asrc = &A[(size_t)(bm + sr) * K + k0 + sh2];
      *(bf8*)&As[sr * 40 + sh2    ] = *(const bf8*)&asrc[0];
      *(bf8*)&As[sr * 40 + sh2 + 8] = *(const bf8*)&asrc[8];
    }
    {
      short tmp[16];
#pragma unroll
      for (int e = 0; e < 16; ++e)
        tmp[e] = f2bf(Bw[(size_t)(k0 + sbk + e) * Nn + bn + sbn]);
      *(bf8*)&Bs[sbn * 40 + sbk    ] = *(bf8*)&tmp[0];
      *(bf8*)&Bs[sbn * 40 + sbk + 8] = *(bf8*)&tmp[8];
    }
    __syncthreads();
    bf8 af[4], bfv[4];
#pragma unroll
    for (int i = 0; i < 4; ++i)
      af[i] = *(const bf8*)&As[(wr * 64 + i * 16 + lr) * 40 + lg * 8];
#pragma unroll
    for (int j = 0; j < 4; ++j)
      bfv[j] = *(const bf8*)&Bs[(wc * 64 + j * 16 + lr) * 40 + lg * 8];
#pragma unroll
    for (int i = 0; i < 4; ++i)
#pragma unroll
      for (int j = 0; j < 4; ++j)
        acc[i][j] = __builtin_amdgcn_mfma_f32_16x16x32_bf16(af[i], bfv[j], acc[i][j], 0, 0, 0);
    __syncthreads();
  }
  float* Ls = (float*)As;
#pragma unroll
  for (int i = 0; i < 4; ++i) {
#pragma unroll
    for (int v = 0; v < 4; ++v) {
      int rl = wr * 64 + i * 16 + lg * 4 + v;
      size_t rowb = (size_t)(bm + rl) * Nn;
      float pe = 0.f;
#pragma unroll
      for (int j = 0; j < 4; ++j) {
        int col = bn + wc * 64 + j * 16 + lr;
        float val = acc[i][j][v];
        if (BIAS) val += bias[col];
        C[rowb + col] = val;
        if (LOSSP) pe += __expf(val);
      }
      if (LOSSP) {
#pragma unroll
        for (int off = 8; off; off >>= 1) pe += __shfl_xor(pe, off);
        if (lr == 0) Ls[rl * 2 + wc] = pe;
      }
    }
  }
  if (LOSSP) {
    __syncthreads();
    if (tid < 128)
      lpart[(size_t)(bm + tid) * 256 + (bn >> 7)] = Ls[tid * 2] + Ls[tid * 2 + 1];
  }
}

// ---------------- fused QK^T + causal softmax + PV --------------------------
__global__ __launch_bounds__(256) void attn_fused(const short* __restrict__ qkv_bf,
    float* __restrict__ maps_l, short* __restrict__ att_bf) {
  __shared__ float S[QT][1032];
  __shared__ short Qs[QT * 72];
  __shared__ short Ks[64 * 72];
  const int tid = threadIdx.x;
  const int q0 = blockIdx.x * QT;
  const int bh = blockIdx.y;
  const int b = bh >> 4, h = bh & 15;
  const int lane = tid & 63, wid = tid >> 6;
  const int lr = lane & 15, lg = lane >> 4;
  if (tid < 128) {                       // stage Q: 16 rows x 64 bf16
    int r = tid >> 3, c8 = (tid & 7) * 8;
    *(bf8*)&Qs[r * 72 + c8] =
      *(const bf8*)&qkv_bf[(size_t)(b * TSEQ + q0 + r) * 3072 + h * 64 + c8];
  }
  const int ktmax = (q0 + QT - 1) / 64 + 1;
  for (int kt = 0; kt < ktmax; ++kt) {
    const int k0 = kt * 64;
    {                                    // stage K tile: 64 rows x 64 bf16
      int r = tid >> 2, c16 = (tid & 3) * 16;
      const short* src = &qkv_bf[(size_t)(b * TSEQ + k0 + r) * 3072 + 1024 + h * 64 + c16];
      *(bf8*)&Ks[r * 72 + c16    ] = *(const bf8*)&src[0];
      *(bf8*)&Ks[r * 72 + c16 + 8] = *(const bf8*)&src[8];
    }
    __syncthreads();
    f32x4 acc = (f32x4)0.f;
#pragma unroll
    for (int ds = 0; ds < 2; ++ds) {
      bf8 af  = *(const bf8*)&Qs[lr * 72 + ds * 32 + lg * 8];
      bf8 bfv = *(const bf8*)&Ks[(wid * 16 + lr) * 72 + ds * 32 + lg * 8];
      acc = __builtin_amdgcn_mfma_f32_16x16x32_bf16(af, bfv, acc, 0, 0, 0);
    }
#pragma unroll
    for (int v = 0; v < 4; ++v)
      S[lg * 4 + v][k0 + wid * 16 + lr] = acc[v] * 0.03125f;
    __syncthreads();
  }
  // row softmax: 16 rows x 16 threads each; P kept in S
  const int r = tid >> 4, l16 = tid & 15;
  const int qg = q0 + r;                 // valid cols 0..qg
  float m = -1e30f;
  for (int c = l16; c <= qg; c += 16) m = fmaxf(m, S[r][c]);
#pragma unroll
  for (int off = 8; off; off >>= 1) m = fmaxf(m, __shfl_xor(m, off, 16));
  float ssum = 0.f;
  for (int c = l16; c <= qg; c += 16) ssum += __expf(S[r][c] - m);
#pragma unroll
  for (int off = 8; off; off >>= 1) ssum += __shfl_xor(ssum, off, 16);
  const float inv = 1.f / ssum;
  for (int c = l16; c <= qg; c += 16)
    S[r][c] = __expf(S[r][c] - m) * inv;
  __syncthreads();
  // coalesced maps write: 16 rows x (256 threads x float4)
  const int c4 = tid * 4;
#pragma unroll 4
  for (int rr = 0; rr < QT; ++rr) {
    const int qgr = q0 + rr;
    float4 p4;
    p4.x = (c4     <= qgr) ? S[rr][c4    ] : 0.f;
    p4.y = (c4 + 1 <= qgr) ? S[rr][c4 + 1] : 0.f;
    p4.z = (c4 + 2 <= qgr) ? S[rr][c4 + 2] : 0.f;
    p4.w = (c4 + 3 <= qgr) ? S[rr][c4 + 3] : 0.f;
    *(float4*)&maps_l[(size_t)bh * TSEQ * TSEQ + (size_t)qgr * TSEQ + c4] = p4;
  }
  __syncthreads();
  // PV: thread (r,l16) owns d = l16*4..+3; V tiles staged into Ks (reuse)
  const int dbase = l16 * 4;
  float4 a = {0.f, 0.f, 0.f, 0.f};
  for (int kt = 0; kt < ktmax; ++kt) {
    const int k0 = kt * 64;
    {
      int vr2 = tid >> 2, vc2 = (tid & 3) * 16;
      const short* src = &qkv_bf[(size_t)(b * TSEQ + k0 + vr2) * 3072 + 2048 + h * 64 + vc2];
      *(bf8*)&Ks[vr2 * 72 + vc2    ] = *(const bf8*)&src[0];
      *(bf8*)&Ks[vr2 * 72 + vc2 + 8] = *(const bf8*)&src[8];
    }
    __syncthreads();
    int kend = qg - k0 + 1;
    if (kend > 64) kend = 64;
    if (kend < 0) kend = 0;
#pragma unroll 4
    for (int k = 0; k < kend; ++k) {
      float p = S[r][k0 + k];
      short4v vv = *(const short4v*)&Ks[k * 72 + dbase];
      a.x += p * bf2f(vv.x); a.y += p * bf2f(vv.y);
      a.z += p * bf2f(vv.z); a.w += p * bf2f(vv.w);
    }
    __syncthreads();
  }
  short* orow = &att_bf[(size_t)(b * TSEQ + qg) * DM + h * 64 + dbase];
  short4v s0;
  s0.x = f2bf(a.x); s0.y = f2bf(a.y); s0.z = f2bf(a.z); s0.w = f2bf(a.w);
  *(short4v*)orow = s0;
}

// ---------------- loss: combine partials; mean-reduce ------------------------
__global__ __launch_bounds__(256) void loss_final(const float* __restrict__ lpart,
    const float* __restrict__ logits, const int* __restrict__ targets,
    float* __restrict__ rowloss) {
  __shared__ float sh[4];
  int row = blockIdx.x, tid = threadIdx.x;
  float s = (tid < VSZ / 128) ? lpart[(size_t)row * 256 + tid] : 0.f;
  s = block_sum256(s, sh);
  if (tid == 0)
    rowloss[row] = logf(s) - logits[(size_t)row * VSZ + targets[row]];
}
__global__ __launch_bounds__(256) void loss_reduce(const float* __restrict__ rowloss,
    float* __restrict__ out) {
  __shared__ float sh[4];
  float s = 0.f;
  for (int i = threadIdx.x; i < NTOK; i += 256) s += rowloss[i];
  s = block_sum256(s, sh);
  if (threadIdx.x == 0) out[0] = s * (1.0f / NTOK);
}

// ============================================================================
extern "C" void kernel_launch(void* const* d_in, const int* in_sizes, int n_in,
                              void* d_out, int out_size, void* d_ws, size_t ws_size,
                              hipStream_t stream) {
  const int*   idx      = (const int*)  d_in[0];
  const int*   targets  = (const int*)  d_in[1];
  const float* word_emb = (const float*)d_in[2];
  const float* pos_emb  = (const float*)d_in[3];
  const float* ln1_g    = (const float*)d_in[4];
  const float* ln1_b    = (const float*)d_in[5];
  const float* wq       = (const float*)d_in[6];
  const float* wk       = (const float*)d_in[7];
  const float* wv       = (const float*)d_in[8];
  const float* proj_w   = (const float*)d_in[9];
  const float* proj_b   = (const float*)d_in[10];
  const float* ln2_g    = (const float*)d_in[11];
  const float* ln2_b    = (const float*)d_in[12];
  const float* ff_w1    = (const float*)d_in[13];
  const float* ff_b1    = (const float*)d_in[14];
  const float* ff_w2    = (const float*)d_in[15];
  const float* ff_b2    = (const float*)d_in[16];
  const float* lnf_g    = (const float*)d_in[17];
  const float* lnf_b    = (const float*)d_in[18];
  const float* lm_w     = (const float*)d_in[19];
  const float* lm_b     = (const float*)d_in[20];

  float* outf   = (float*)d_out;
  float* logits = outf + LOGITS_OFF;
  float* lossp  = outf + LOSS_OFF;
  float* maps   = outf + MAPS_OFF;
  float* probs  = outf + PROBS_OFF;

  const size_t ND = (size_t)NTOK * DM;
  // ---- activation scratch in d_ws (~52 MB) ----
  float* x    = (float*)d_ws;                 // ND f32
  float* rowloss = x + ND;                    // NTOK f32
  float* lpart   = rowloss + NTOK;            // NTOK*256 f32 (2 MB)
  short* qkv_bf = (short*)(lpart + (size_t)NTOK * 256);  // 3*ND bf16
  short* h_bf   = qkv_bf + 3 * ND;            // ND bf16
  short* att_bf = h_bf + ND;                  // ND bf16
  short* ffh_bf = att_bf + ND;                // NTOK*FFD bf16
  short* xf_bf  = ffh_bf + (size_t)NTOK * FFD;// ND bf16
  char*  ws_end = (char*)(xf_bf + ND);
  const size_t act_bytes = (size_t)(ws_end - (char*)d_ws);
  const size_t lmwt_bytes = (size_t)VSZ * DM * sizeof(short);
  const int lm_fast = (ws_size >= act_bytes + lmwt_bytes);
  short* lm_wt = (short*)ws_end;

  short* wt_base = (short*)logits;            // bf16 layer weights in logits slot
  auto layer_wt = [&](int l) { return wt_base + (size_t)l * PLW; };

  dim3 b256(256);
  const int tr_blocks = 2 * 3072 + (lm_fast ? 8000 : 0);
  transpose_all<<<dim3(tr_blocks), b256, 0, stream>>>(wq, wk, wv, proj_w, ff_w1, ff_w2,
                                                      wt_base, lm_w, lm_wt);

  embed_kernel<<<dim3((NTOK * DM) / 256), b256, 0, stream>>>(idx, word_emb, pos_emb, x);

  for (int l = 0; l < LL; ++l) {
    short* qkvt = layer_wt(l);
    short* projt = qkvt + (size_t)3 * DM * DM;
    short* ff1t  = projt + (size_t)DM * DM;
    short* ff2t  = ff1t + (size_t)DM * FFD;
    ln_bf<<<dim3(NTOK), b256, 0, stream>>>(x, ln1_g + l * DM, ln1_b + l * DM, h_bf);
    gemm_bb<0,0,0,1,0><<<dim3(NTOK/128, 3072/128), b256, 0, stream>>>(h_bf, DM, qkvt, nullptr, qkv_bf, NTOK, DM, 3072, nullptr);
    float* maps_l = maps + (size_t)l * BB * HH * TSEQ * TSEQ;
    attn_fused<<<dim3(TSEQ/QT, BB*HH), b256, 0, stream>>>(qkv_bf, maps_l, att_bf);
    gemm_bb<1,1,0,0,0><<<dim3(NTOK/128, DM/128), b256, 0, stream>>>(att_bf, DM, projt, proj_b + l * DM, x, NTOK, DM, DM, nullptr);
    ln_bf<<<dim3(NTOK), b256, 0, stream>>>(x, ln2_g + l * DM, ln2_b + l * DM, h_bf);
    gemm_bb<1,0,1,1,0><<<dim3(NTOK/128, FFD/128), b256, 0, stream>>>(h_bf, DM, ff1t, ff_b1 + l * FFD, ffh_bf, NTOK, DM, FFD, nullptr);
    gemm_bb<1,1,0,0,0><<<dim3(NTOK/128, DM/128), b256, 0, stream>>>(ffh_bf, FFD, ff2t, ff_b2 + l * DM, x, NTOK, FFD, DM, nullptr);
  }

  ln_probs<<<dim3(NTOK), b256, 0, stream>>>(x, lnf_g, lnf_b, xf_bf, probs);
  if (lm_fast)
    gemm_bb<1,0,0,0,1><<<dim3(NTOK/128, VSZ/128), b256, 0, stream>>>(xf_bf, DM, lm_wt, lm_b, logits, NTOK, DM, VSZ, lpart);
  else
    gemm_lm_cvt<1,1><<<dim3(NTOK/128, VSZ/128), b256, 0, stream>>>(xf_bf, lm_w, lm_b, logits, NTOK, DM, VSZ, lpart);
  loss_final<<<dim3(NTOK), b256, 0, stream>>>(lpart, logits, targets, rowloss);
  loss_reduce<<<dim3(1), b256, 0, stream>>>(rowloss, lossp);

  (void)in_sizes; (void)n_in; (void)out_size;
}